// Round 12
// baseline (397.658 us; speedup 1.0000x reference)
//
#include <hip/hip_runtime.h>
#include <hip/hip_bf16.h>

typedef __attribute__((ext_vector_type(8))) short short8;
typedef __attribute__((ext_vector_type(4))) short short4_t;
typedef __attribute__((ext_vector_type(4))) float f32x4;
typedef unsigned short ushort_t;

#define DEV __device__ __forceinline__

DEV ushort_t f2bf(float f) {
    unsigned u = __builtin_bit_cast(unsigned, f);
    u = u + 0x7fffu + ((u >> 16) & 1u);   // RNE
    return (ushort_t)(u >> 16);
}

DEV unsigned pk_bf16(float lo, float hi) {
    __hip_bfloat162 h = __float22bfloat162_rn(make_float2(lo, hi));
    unsigned u;
    __builtin_memcpy(&u, &h, sizeof(u));
    return u;
}

// raw v_exp_f32: single TRANS-pipe instr; exact in our argument range.
DEV float fast_exp2(float x) {
#if __has_builtin(__builtin_amdgcn_exp2f)
    return __builtin_amdgcn_exp2f(x);
#else
    float r;
    asm("v_exp_f32 %0, %1" : "=v"(r) : "v"(x));
    return r;
#endif
}

DEV short8 ld8(const ushort_t* p) { return *reinterpret_cast<const short8*>(p); }

// ---------------------------------------------------------------------------
// prep: f32 -> bf16 elementwise (grid*256*8 == n exactly)
// ---------------------------------------------------------------------------
__global__ __launch_bounds__(256)
void cvt_bf16(const float* __restrict__ in, ushort_t* __restrict__ out)
{
    const size_t i = ((size_t)blockIdx.x * 256 + threadIdx.x) * 8;
    const float4 a = *reinterpret_cast<const float4*>(in + i);
    const float4 b = *reinterpret_cast<const float4*>(in + i + 4);
    short8 v;
    v[0] = (short)f2bf(a.x); v[1] = (short)f2bf(a.y);
    v[2] = (short)f2bf(a.z); v[3] = (short)f2bf(a.w);
    v[4] = (short)f2bf(b.x); v[5] = (short)f2bf(b.y);
    v[6] = (short)f2bf(b.z); v[7] = (short)f2bf(b.w);
    *reinterpret_cast<short8*>(out + i) = v;
}

// ---------------------------------------------------------------------------
// prep: W[K][N] f32 -> Wt[N][K] bf16 (64x64 tiles via LDS)
// ---------------------------------------------------------------------------
__global__ __launch_bounds__(256)
void tcvt_bf16(const float* __restrict__ W, ushort_t* __restrict__ Wt, int K, int N)
{
    __shared__ ushort_t tile[64][72];
    const int t = threadIdx.x;
    const int nx = blockIdx.x * 64, ky = blockIdx.y * 64;
    const int r = t >> 2, q = (t & 3) * 16;

    const float* src = W + (size_t)(ky + r) * N + nx + q;
#pragma unroll
    for (int i = 0; i < 4; ++i) {
        const float4 v = *reinterpret_cast<const float4*>(src + 4 * i);
        tile[r][q + 4 * i + 0] = f2bf(v.x);
        tile[r][q + 4 * i + 1] = f2bf(v.y);
        tile[r][q + 4 * i + 2] = f2bf(v.z);
        tile[r][q + 4 * i + 3] = f2bf(v.w);
    }
    __syncthreads();
    short8 o0, o1;
#pragma unroll
    for (int i = 0; i < 8; ++i) {
        o0[i] = (short)tile[q + i][r];
        o1[i] = (short)tile[q + 8 + i][r];
    }
    ushort_t* dst = Wt + (size_t)(nx + r) * K + ky + q;
    *reinterpret_cast<short8*>(dst) = o0;
    *reinterpret_cast<short8*>(dst + 8) = o1;
}

// ---------------------------------------------------------------------------
// Fused projections (fast path): nblk<8 -> Q = A1 @ WqT; else KV = A2 @ WkvT.
// ---------------------------------------------------------------------------
__global__ __launch_bounds__(256, 2)
void proj_all(const ushort_t* __restrict__ A1, const ushort_t* __restrict__ A2,
              const ushort_t* __restrict__ Wqt, const ushort_t* __restrict__ Wkvt,
              const float* __restrict__ bqv, const float* __restrict__ bkv,
              ushort_t* __restrict__ Qr, ushort_t* __restrict__ Kr,
              ushort_t* __restrict__ Vt)
{
    __shared__ ushort_t As[128 * 72];
    __shared__ ushort_t Bs[128 * 72];

    const int t = threadIdx.x;
    const int lane = t & 63;
    const int wv = t >> 6;
    const int wr = wv >> 1, wc = wv & 1;
    const int c = lane & 15, g = lane >> 4;
    const int m0 = blockIdx.y * 128;
    const int nblk = blockIdx.x;

    const ushort_t* A;
    const ushort_t* Wt;
    const float* bias;
    int n0;
    if (nblk < 8) { A = A1; Wt = Wqt;  bias = bqv; n0 = nblk * 128; }
    else          { A = A2; Wt = Wkvt; bias = bkv; n0 = (nblk - 8) * 128; }
    const bool isQ = (nblk < 8);

    f32x4 acc[4][4];
    const f32x4 zero4 = {0.f, 0.f, 0.f, 0.f};
#pragma unroll
    for (int mi = 0; mi < 4; ++mi)
#pragma unroll
        for (int ni = 0; ni < 4; ++ni) acc[mi][ni] = zero4;

    const int srow[4] = { (t + 0)   >> 3, (t + 256) >> 3, (t + 512) >> 3, (t + 768) >> 3 };
    const int skq     = (t & 7) * 8;

    short8 a_reg[4], b_reg[4];
#pragma unroll
    for (int rep = 0; rep < 4; ++rep) {
        a_reg[rep] = ld8(A  + (size_t)(m0 + srow[rep]) * 1024 + skq);
        b_reg[rep] = ld8(Wt + (size_t)(n0 + srow[rep]) * 1024 + skq);
    }

    for (int it = 0; it < 16; ++it) {
#pragma unroll
        for (int rep = 0; rep < 4; ++rep) {
            *reinterpret_cast<short8*>(&As[srow[rep] * 72 + skq]) = a_reg[rep];
            *reinterpret_cast<short8*>(&Bs[srow[rep] * 72 + skq]) = b_reg[rep];
        }
        __syncthreads();
        if (it < 15) {
            const int k1 = (it + 1) * 64;
#pragma unroll
            for (int rep = 0; rep < 4; ++rep) {
                a_reg[rep] = ld8(A  + (size_t)(m0 + srow[rep]) * 1024 + k1 + skq);
                b_reg[rep] = ld8(Wt + (size_t)(n0 + srow[rep]) * 1024 + k1 + skq);
            }
        }
#pragma unroll
        for (int kk = 0; kk < 64; kk += 32) {
            short8 afr[4], bfr[4];
#pragma unroll
            for (int mi = 0; mi < 4; ++mi)
                afr[mi] = ld8(&As[(wr * 64 + mi * 16 + c) * 72 + kk + 8 * g]);
#pragma unroll
            for (int ni = 0; ni < 4; ++ni)
                bfr[ni] = ld8(&Bs[(wc * 64 + ni * 16 + c) * 72 + kk + 8 * g]);
#pragma unroll
            for (int mi = 0; mi < 4; ++mi)
#pragma unroll
                for (int ni = 0; ni < 4; ++ni)
                    acc[mi][ni] = __builtin_amdgcn_mfma_f32_16x16x32_bf16(
                        afr[mi], bfr[ni], acc[mi][ni], 0, 0, 0);
        }
        __syncthreads();
    }

#pragma unroll
    for (int mi = 0; mi < 4; ++mi) {
#pragma unroll
        for (int ni = 0; ni < 4; ++ni) {
            const int n = n0 + wc * 64 + ni * 16 + c;
            const float bb = bias[n];
#pragma unroll
            for (int j = 0; j < 4; ++j) {
                const int m = m0 + wr * 64 + mi * 16 + 4 * g + j;
                const int b = m >> 11, s = m & 2047;
                const ushort_t val = f2bf(acc[mi][ni][j] + bb);
                if (isQ) {
                    Qr[((size_t)((b * 16 + (n >> 6)) * 2048 + s)) * 64 + (n & 63)] = val;
                } else if (n < 1024) {
                    Kr[((size_t)((b * 16 + (n >> 6)) * 2048 + s)) * 64 + (n & 63)] = val;
                } else {
                    const int np = n - 1024;
                    Vt[(size_t)((b * 16 + (np >> 6)) * 64 + (np & 63)) * 2048 + s] = val;
                }
            }
        }
    }
}

// ---------------------------------------------------------------------------
// Fallback projection (r3/r8-proven): used if ws_size is too small for prep.
// ---------------------------------------------------------------------------
__global__ __launch_bounds__(256)
void proj_gemm(const float* __restrict__ A, const float* __restrict__ W,
               const float* __restrict__ bias, int N,
               ushort_t* __restrict__ outRow, ushort_t* __restrict__ outT)
{
    __shared__ ushort_t As[128 * 72];
    __shared__ ushort_t Bt[128 * 72];

    const int t = threadIdx.x;
    const int lane = t & 63;
    const int wv = t >> 6;
    const int wr = wv >> 1, wc = wv & 1;
    const int c = lane & 15, g = lane >> 4;
    const int m0 = blockIdx.y * 128, n0 = blockIdx.x * 128;

    f32x4 acc[4][4];
    const f32x4 zero4 = {0.f, 0.f, 0.f, 0.f};
#pragma unroll
    for (int mi = 0; mi < 4; ++mi)
#pragma unroll
        for (int ni = 0; ni < 4; ++ni) acc[mi][ni] = zero4;

    for (int it = 0; it < 16; ++it) {
        const int k0 = it * 64;
        {
            const int kq = (t & 15) * 4;
            int r = t >> 4;
#pragma unroll
            for (int rep = 0; rep < 8; ++rep, r += 16) {
                float4 v = *reinterpret_cast<const float4*>(
                    A + (size_t)(m0 + r) * 1024 + k0 + kq);
                ushort_t* dst = &As[r * 72 + kq];
                dst[0] = f2bf(v.x); dst[1] = f2bf(v.y);
                dst[2] = f2bf(v.z); dst[3] = f2bf(v.w);
            }
        }
        {
            const int nq = (t & 31) * 4;
            const int kr = t >> 5;
#pragma unroll
            for (int rep = 0; rep < 8; ++rep) {
                const int k = kr + 8 * rep;
                float4 v = *reinterpret_cast<const float4*>(
                    W + (size_t)(k0 + k) * N + n0 + nq);
                Bt[(nq + 0) * 72 + k] = f2bf(v.x);
                Bt[(nq + 1) * 72 + k] = f2bf(v.y);
                Bt[(nq + 2) * 72 + k] = f2bf(v.z);
                Bt[(nq + 3) * 72 + k] = f2bf(v.w);
            }
        }
        __syncthreads();
#pragma unroll
        for (int kk = 0; kk < 64; kk += 32) {
            short8 afr[4], bfr[4];
#pragma unroll
            for (int mi = 0; mi < 4; ++mi)
                afr[mi] = ld8(&As[(wr * 64 + mi * 16 + c) * 72 + kk + 8 * g]);
#pragma unroll
            for (int ni = 0; ni < 4; ++ni)
                bfr[ni] = ld8(&Bt[(wc * 64 + ni * 16 + c) * 72 + kk + 8 * g]);
#pragma unroll
            for (int mi = 0; mi < 4; ++mi)
#pragma unroll
                for (int ni = 0; ni < 4; ++ni)
                    acc[mi][ni] = __builtin_amdgcn_mfma_f32_16x16x32_bf16(
                        afr[mi], bfr[ni], acc[mi][ni], 0, 0, 0);
        }
        __syncthreads();
    }

#pragma unroll
    for (int mi = 0; mi < 4; ++mi) {
#pragma unroll
        for (int ni = 0; ni < 4; ++ni) {
            const int n = n0 + wc * 64 + ni * 16 + c;
            const float bb = bias[n];
#pragma unroll
            for (int j = 0; j < 4; ++j) {
                const int m = m0 + wr * 64 + mi * 16 + 4 * g + j;
                const int b = m >> 11, s = m & 2047;
                const ushort_t val = f2bf(acc[mi][ni][j] + bb);
                if (outT != nullptr && n >= 1024) {
                    const int np = n - 1024;
                    const int hh = np >> 6, d = np & 63;
                    outT[(size_t)((b * 16 + hh) * 64 + d) * 2048 + s] = val;
                } else {
                    const int hh = n >> 6, d = n & 63;
                    outRow[((size_t)((b * 16 + hh) * 2048 + s)) * 64 + d] = val;
                }
            }
        }
    }
}

// ---------------------------------------------------------------------------
// Flash attention: fixed-max softmax (v_exp_f32), PV^T, LDS double-buffered
// staging, in-block kv-split (wq = w&1: 2 q-waves x 32 rows; wk = w>>1: kv
// half). Each half stages its own K/V tiles; cross-half merge is a pure SUM
// through an LDS overlay of the dead staging buffers (fixed-max => no max
// bookkeeping). 1024 blocks -> 4 blocks/CU -> 16 waves/CU (50% occupancy).
// ---------------------------------------------------------------------------
DEV void attn_body(const ushort_t* __restrict__ khh, const ushort_t* __restrict__ vhh,
                   const float* __restrict__ crh, int kv_next,
                   const ushort_t* KsC, const ushort_t* VsC,
                   ushort_t* KsN, ushort_t* VsN,
                   int c, int g,
                   int krow0, int krow1, int kcol,
                   int vrow0, int vrow1, int vcol,
                   const short8 (&bq)[2][2],
                   float4 (&CC)[2][2], float4 (&CN)[2][2],
                   f32x4 (&accv)[2][4], float (&lst)[2],
                   float (&a0s)[2], float (&a1s)[2])
{
    const f32x4 zero4 = {0.f, 0.f, 0.f, 0.f};
    const float SCL = 0.18033688011112042f;  // (1/8) * log2(e)

    // ---- issue next-tile staging loads (this half's tile); pinned above compute
    const short8 kreg0 = ld8(khh + (size_t)(kv_next + krow0) * 64 + kcol);
    const short8 kreg1 = ld8(khh + (size_t)(kv_next + krow1) * 64 + kcol);
    const short8 vreg0 = ld8(vhh + (size_t)vrow0 * 2048 + kv_next + vcol);
    const short8 vreg1 = ld8(vhh + (size_t)vrow1 * 2048 + kv_next + vcol);
    {
        const float* cp0 = crh + (size_t)(kv_next + 4 * g) * 2;
        CN[0][0] = *reinterpret_cast<const float4*>(cp0);
        CN[0][1] = *reinterpret_cast<const float4*>(cp0 + 4);
        const float* cp1 = crh + (size_t)(kv_next + 16 + 4 * g) * 2;
        CN[1][0] = *reinterpret_cast<const float4*>(cp1);
        CN[1][1] = *reinterpret_cast<const float4*>(cp1 + 4);
    }
    __builtin_amdgcn_sched_barrier(0);

    // ---- LDS -> fragments ----
    short8 KC[2][2];
#pragma unroll
    for (int ct = 0; ct < 2; ++ct)
#pragma unroll
        for (int st = 0; st < 2; ++st)
            KC[ct][st] = ld8(&KsC[(ct * 16 + c) * 72 + st * 32 + 8 * g]);
    short8 VC[4];
#pragma unroll
    for (int dt = 0; dt < 4; ++dt) {
        const short4_t vlo = *reinterpret_cast<const short4_t*>(&VsC[(dt * 16 + c) * 40 + 4 * g]);
        const short4_t vhi = *reinterpret_cast<const short4_t*>(&VsC[(dt * 16 + c) * 40 + 4 * g + 16]);
        VC[dt] = __builtin_shufflevector(vlo, vhi, 0, 1, 2, 3, 4, 5, 6, 7);
    }

    // ---- QK^T (swapped): lane holds S^T[kv=16ct+4g+j][q=c] ----
    f32x4 sc[2][2];
#pragma unroll
    for (int qt = 0; qt < 2; ++qt)
#pragma unroll
        for (int ct = 0; ct < 2; ++ct) {
            f32x4 z = zero4;
            z = __builtin_amdgcn_mfma_f32_16x16x32_bf16(KC[ct][0], bq[qt][0], z, 0, 0, 0);
            z = __builtin_amdgcn_mfma_f32_16x16x32_bf16(KC[ct][1], bq[qt][1], z, 0, 0, 0);
            sc[qt][ct] = z;
        }

    // ---- fixed-max softmax + rank-2 cr accumulation ----
    short8 pa[2];
#pragma unroll
    for (int qt = 0; qt < 2; ++qt) {
        float e[2][4];
        float lc = lst[qt], a0c = a0s[qt], a1c = a1s[qt];
#pragma unroll
        for (int ct = 0; ct < 2; ++ct) {
            const float cr0[4] = {CC[ct][0].x, CC[ct][0].z, CC[ct][1].x, CC[ct][1].z};
            const float cr1[4] = {CC[ct][0].y, CC[ct][0].w, CC[ct][1].y, CC[ct][1].w};
#pragma unroll
            for (int j = 0; j < 4; ++j) {
                const float ev = fast_exp2(sc[qt][ct][j] * SCL);
                e[ct][j] = ev;
                lc  += ev;
                a0c += ev * cr0[j];
                a1c += ev * cr1[j];
            }
        }
        lst[qt] = lc; a0s[qt] = a0c; a1s[qt] = a1c;
        int4 w;
        w.x = (int)pk_bf16(e[0][0], e[0][1]);
        w.y = (int)pk_bf16(e[0][2], e[0][3]);
        w.z = (int)pk_bf16(e[1][0], e[1][1]);
        w.w = (int)pk_bf16(e[1][2], e[1][3]);
        pa[qt] = __builtin_bit_cast(short8, w);
    }

    // ---- PV^T: A=V gathered in the same kv-slot permutation as P ----
#pragma unroll
    for (int dt = 0; dt < 4; ++dt) {
        accv[0][dt] = __builtin_amdgcn_mfma_f32_16x16x32_bf16(VC[dt], pa[0], accv[0][dt], 0, 0, 0);
        accv[1][dt] = __builtin_amdgcn_mfma_f32_16x16x32_bf16(VC[dt], pa[1], accv[1][dt], 0, 0, 0);
    }

    // ---- write staged tile into next buffer; one barrier per body ----
    *reinterpret_cast<short8*>(&KsN[krow0 * 72 + kcol]) = kreg0;
    *reinterpret_cast<short8*>(&KsN[krow1 * 72 + kcol]) = kreg1;
    *reinterpret_cast<short8*>(&VsN[vrow0 * 40 + vcol]) = vreg0;
    *reinterpret_cast<short8*>(&VsN[vrow1 * 40 + vcol]) = vreg1;
    __syncthreads();
}

__global__ __launch_bounds__(256, 4)
void attn_kernel(const ushort_t* __restrict__ Qr, const ushort_t* __restrict__ Kr,
                 const ushort_t* __restrict__ Vt, const float* __restrict__ cr,
                 const float* __restrict__ Wmo, const float* __restrict__ bmo,
                 float* __restrict__ out)
{
    // 38912 B: K(half,buf) @ (half*2+buf)*2304 shorts; V(half,buf) @ 9216 +
    // (half*2+buf)*2560. Merge overlay (20 KB of floats) reuses this space.
    __shared__ short8 smem16[2432];
    ushort_t* smem = (ushort_t*)smem16;

    const int t = threadIdx.x;
    const int w = t >> 6, lane = t & 63;
    const int wq = w & 1, wk = w >> 1;
    const int c = lane & 15, g = lane >> 4;
    const int th = t & 127;

    // staging chunk map (per half: 128 threads stage 32x64 K + 64x32 V)
    const int krow0 = th >> 3,          krow1 = (th + 128) >> 3, kcol = (th & 7) * 8;
    const int vrow0 = th >> 2,          vrow1 = (th + 128) >> 2, vcol = (th & 3) * 8;

    // XCD swizzle: gid%8 ~ XCD; each XCD sees 4 distinct (b,h) pairs.
    const int gid = blockIdx.x;
    const int bh = (gid & 7) + 8 * ((gid >> 3) & 3);
    const int xt = gid >> 5;                // 0..31
    const int b = bh >> 4, hh = bh & 15;
    const int qb = xt * 64 + wq * 32;

    const ushort_t* Qh = Qr + (size_t)bh * (2048 * 64);
    const ushort_t* Kh = Kr + (size_t)bh * (2048 * 64);
    const ushort_t* Vh = Vt + (size_t)bh * (64 * 2048);
    const float*   crb = cr + (size_t)b * (2048 * 2);

    // this half's kv window
    const ushort_t* khh = Kh + (size_t)(wk * 1024) * 64;
    const ushort_t* vhh = Vh + wk * 1024;
    const float*    crh = crb + (size_t)(wk * 1024) * 2;

    ushort_t* Kbuf0 = smem + (wk * 2 + 0) * 2304;
    ushort_t* Kbuf1 = smem + (wk * 2 + 1) * 2304;
    ushort_t* Vbuf0 = smem + 9216 + (wk * 2 + 0) * 2560;
    ushort_t* Vbuf1 = smem + 9216 + (wk * 2 + 1) * 2560;

    short8 bq[2][2];
#pragma unroll
    for (int qt = 0; qt < 2; ++qt)
#pragma unroll
        for (int st = 0; st < 2; ++st)
            bq[qt][st] = ld8(Qh + (size_t)(qb + qt * 16 + c) * 64 + st * 32 + 8 * g);

    f32x4 accv[2][4];
    const f32x4 zero4 = {0.f, 0.f, 0.f, 0.f};
#pragma unroll
    for (int qt = 0; qt < 2; ++qt)
#pragma unroll
        for (int dt = 0; dt < 4; ++dt) accv[qt][dt] = zero4;

    float lst[2] = {0.f, 0.f};
    float a0s[2] = {0.f, 0.f};
    float a1s[2] = {0.f, 0.f};

    float4 cA[2][2], cB[2][2];

    // prologue: stage local tile 0 into buf0, cr tile 0 into cA
    {
        *reinterpret_cast<short8*>(&Kbuf0[krow0 * 72 + kcol]) =
            ld8(khh + (size_t)krow0 * 64 + kcol);
        *reinterpret_cast<short8*>(&Kbuf0[krow1 * 72 + kcol]) =
            ld8(khh + (size_t)krow1 * 64 + kcol);
        *reinterpret_cast<short8*>(&Vbuf0[vrow0 * 40 + vcol]) =
            ld8(vhh + (size_t)vrow0 * 2048 + vcol);
        *reinterpret_cast<short8*>(&Vbuf0[vrow1 * 40 + vcol]) =
            ld8(vhh + (size_t)vrow1 * 2048 + vcol);
        const float* cp0 = crh + (size_t)(4 * g) * 2;
        cA[0][0] = *reinterpret_cast<const float4*>(cp0);
        cA[0][1] = *reinterpret_cast<const float4*>(cp0 + 4);
        const float* cp1 = crh + (size_t)(16 + 4 * g) * 2;
        cA[1][0] = *reinterpret_cast<const float4*>(cp1);
        cA[1][1] = *reinterpret_cast<const float4*>(cp1 + 4);
    }
    __syncthreads();

    for (int i = 0; i < 16; ++i) {
        const int kvb = i * 64;
        attn_body(khh, vhh, crh, kvb + 32,
                  Kbuf0, Vbuf0, Kbuf1, Vbuf1,
                  c, g, krow0, krow1, kcol, vrow0, vrow1, vcol,
                  bq, cA, cB, accv, lst, a0s, a1s);
        attn_body(khh, vhh, crh, (kvb + 64) & 1023,
                  Kbuf1, Vbuf1, Kbuf0, Vbuf0,
                  c, g, krow0, krow1, kcol, vrow0, vrow1, vcol,
                  bq, cB, cA, accv, lst, a0s, a1s);
    }

    // cross-half merge: pure sums via LDS overlay of the (dead) staging area
    float* my = reinterpret_cast<float*>(smem16) + ((size_t)(wq * 64 + lane)) * 40;
    if (wk == 1) {
#pragma unroll
        for (int qt = 0; qt < 2; ++qt)
#pragma unroll
            for (int dt = 0; dt < 4; ++dt)
#pragma unroll
                for (int j = 0; j < 4; ++j) my[qt * 16 + dt * 4 + j] = accv[qt][dt][j];
#pragma unroll
        for (int qt = 0; qt < 2; ++qt) {
            my[32 + qt] = lst[qt]; my[34 + qt] = a0s[qt]; my[36 + qt] = a1s[qt];
        }
    }
    __syncthreads();
    if (wk != 0) return;

#pragma unroll
    for (int qt = 0; qt < 2; ++qt) {
#pragma unroll
        for (int dt = 0; dt < 4; ++dt)
#pragma unroll
            for (int j = 0; j < 4; ++j) accv[qt][dt][j] += my[qt * 16 + dt * 4 + j];
        lst[qt] += my[32 + qt]; a0s[qt] += my[34 + qt]; a1s[qt] += my[36 + qt];
        // reduce stats across g (kv-subsets): every lane gets q=c totals
        lst[qt] += __shfl_xor(lst[qt], 16, 64); lst[qt] += __shfl_xor(lst[qt], 32, 64);
        a0s[qt] += __shfl_xor(a0s[qt], 16, 64); a0s[qt] += __shfl_xor(a0s[qt], 32, 64);
        a1s[qt] += __shfl_xor(a1s[qt], 16, 64); a1s[qt] += __shfl_xor(a1s[qt], 32, 64);
    }

    // epilogue: accv[qt][dt] reg j -> q = qb+qt*16+c, d = dt*16+4g+j
#pragma unroll
    for (int qt = 0; qt < 2; ++qt) {
        const int q = qb + qt * 16 + c;
        const float inv = 1.f / lst[qt];
        const float a0 = a0s[qt] * inv, a1 = a1s[qt] * inv;
#pragma unroll
        for (int dt = 0; dt < 4; ++dt) {
            const int d = hh * 64 + dt * 16 + 4 * g;
            const float4 w0 = *reinterpret_cast<const float4*>(Wmo + d);
            const float4 w1 = *reinterpret_cast<const float4*>(Wmo + 1024 + d);
            const float4 bm = *reinterpret_cast<const float4*>(bmo + d);
            const size_t oidx = ((size_t)(b * 2048 + q)) * 1024 + d;
            float4 hv, mv;
            hv.x = accv[qt][dt][0] * inv; hv.y = accv[qt][dt][1] * inv;
            hv.z = accv[qt][dt][2] * inv; hv.w = accv[qt][dt][3] * inv;
            mv.x = a0 * w0.x + a1 * w1.x + bm.x;
            mv.y = a0 * w0.y + a1 * w1.y + bm.y;
            mv.z = a0 * w0.z + a1 * w1.z + bm.z;
            mv.w = a0 * w0.w + a1 * w1.w + bm.w;
            *reinterpret_cast<float4*>(out + oidx) = hv;
            *reinterpret_cast<float4*>(out + 4194304 + oidx) = mv;
        }
    }
}

// ---------------------------------------------------------------------------
extern "C" void kernel_launch(void* const* d_in, const int* in_sizes, int n_in,
                              void* d_out, int out_size, void* d_ws, size_t ws_size,
                              hipStream_t stream)
{
    const float* i1  = (const float*)d_in[0];
    const float* i2  = (const float*)d_in[1];
    const float* cr  = (const float*)d_in[2];
    const float* Wq  = (const float*)d_in[3];
    const float* bq  = (const float*)d_in[4];
    const float* Wkv = (const float*)d_in[5];
    const float* bkv = (const float*)d_in[6];
    const float* Wmo = (const float*)d_in[7];
    const float* bmo = (const float*)d_in[8];
    float* out = (float*)d_out;

    ushort_t* Qr = (ushort_t*)d_ws;          // [2,16,2048,64] bf16 (8 MB)
    ushort_t* Kr = Qr + 4194304;             // [2,16,2048,64] bf16 (8 MB)
    ushort_t* Vt = Kr + 4194304;             // [2,16,64,2048] bf16 (8 MB)

    // fast path needs 46 MB of ws: + A1(8) A2(8) Wqt(2) Wkvt(4)
    if (ws_size >= 48234496ULL) {
        ushort_t* A1   = Vt + 4194304;
        ushort_t* A2   = A1 + 4194304;
        ushort_t* Wqt  = A2 + 4194304;
        ushort_t* Wkvt = Wqt + 1048576;
        cvt_bf16<<<dim3(2048), dim3(256), 0, stream>>>(i1, A1);
        cvt_bf16<<<dim3(2048), dim3(256), 0, stream>>>(i2, A2);
        tcvt_bf16<<<dim3(16, 16), dim3(256), 0, stream>>>(Wq, Wqt, 1024, 1024);
        tcvt_bf16<<<dim3(32, 16), dim3(256), 0, stream>>>(Wkv, Wkvt, 1024, 2048);
        proj_all<<<dim3(24, 32), dim3(256), 0, stream>>>(A1, A2, Wqt, Wkvt, bq, bkv, Qr, Kr, Vt);
    } else {
        proj_gemm<<<dim3(8, 32), dim3(256), 0, stream>>>(i1, Wq, bq, 1024, Qr, nullptr);
        proj_gemm<<<dim3(16, 32), dim3(256), 0, stream>>>(i2, Wkv, bkv, 2048, Kr, Vt);
    }
    attn_kernel<<<dim3(1024), dim3(256), 0, stream>>>(Qr, Kr, Vt, cr, Wmo, bmo, out);
}

// Round 13
// 139.860 us; speedup vs baseline: 2.8433x; 2.8433x over previous
//
#include <hip/hip_runtime.h>
#include <hip/hip_bf16.h>

typedef __attribute__((ext_vector_type(8))) short short8;
typedef __attribute__((ext_vector_type(4))) short short4_t;
typedef __attribute__((ext_vector_type(4))) float f32x4;
typedef unsigned short ushort_t;

#define DEV __device__ __forceinline__

DEV ushort_t f2bf(float f) {
    unsigned u = __builtin_bit_cast(unsigned, f);
    u = u + 0x7fffu + ((u >> 16) & 1u);   // RNE
    return (ushort_t)(u >> 16);
}

DEV unsigned pk_bf16(float lo, float hi) {
    __hip_bfloat162 h = __float22bfloat162_rn(make_float2(lo, hi));
    unsigned u;
    __builtin_memcpy(&u, &h, sizeof(u));
    return u;
}

// raw v_exp_f32: single TRANS-pipe instr; exact in our argument range.
DEV float fast_exp2(float x) {
#if __has_builtin(__builtin_amdgcn_exp2f)
    return __builtin_amdgcn_exp2f(x);
#else
    float r;
    asm("v_exp_f32 %0, %1" : "=v"(r) : "v"(x));
    return r;
#endif
}

DEV short8 ld8(const ushort_t* p) { return *reinterpret_cast<const short8*>(p); }

// ---------------------------------------------------------------------------
// prep: f32 -> bf16 elementwise (grid*256*8 == n exactly)
// ---------------------------------------------------------------------------
__global__ __launch_bounds__(256)
void cvt_bf16(const float* __restrict__ in, ushort_t* __restrict__ out)
{
    const size_t i = ((size_t)blockIdx.x * 256 + threadIdx.x) * 8;
    const float4 a = *reinterpret_cast<const float4*>(in + i);
    const float4 b = *reinterpret_cast<const float4*>(in + i + 4);
    short8 v;
    v[0] = (short)f2bf(a.x); v[1] = (short)f2bf(a.y);
    v[2] = (short)f2bf(a.z); v[3] = (short)f2bf(a.w);
    v[4] = (short)f2bf(b.x); v[5] = (short)f2bf(b.y);
    v[6] = (short)f2bf(b.z); v[7] = (short)f2bf(b.w);
    *reinterpret_cast<short8*>(out + i) = v;
}

// ---------------------------------------------------------------------------
// prep: W[K][N] f32 -> Wt[N][K] bf16 (64x64 tiles via LDS)
// ---------------------------------------------------------------------------
__global__ __launch_bounds__(256)
void tcvt_bf16(const float* __restrict__ W, ushort_t* __restrict__ Wt, int K, int N)
{
    __shared__ ushort_t tile[64][72];
    const int t = threadIdx.x;
    const int nx = blockIdx.x * 64, ky = blockIdx.y * 64;
    const int r = t >> 2, q = (t & 3) * 16;

    const float* src = W + (size_t)(ky + r) * N + nx + q;
#pragma unroll
    for (int i = 0; i < 4; ++i) {
        const float4 v = *reinterpret_cast<const float4*>(src + 4 * i);
        tile[r][q + 4 * i + 0] = f2bf(v.x);
        tile[r][q + 4 * i + 1] = f2bf(v.y);
        tile[r][q + 4 * i + 2] = f2bf(v.z);
        tile[r][q + 4 * i + 3] = f2bf(v.w);
    }
    __syncthreads();
    short8 o0, o1;
#pragma unroll
    for (int i = 0; i < 8; ++i) {
        o0[i] = (short)tile[q + i][r];
        o1[i] = (short)tile[q + 8 + i][r];
    }
    ushort_t* dst = Wt + (size_t)(nx + r) * K + ky + q;
    *reinterpret_cast<short8*>(dst) = o0;
    *reinterpret_cast<short8*>(dst + 8) = o1;
}

// ---------------------------------------------------------------------------
// Fused projections (fast path): nblk<8 -> Q = A1 @ WqT; else KV = A2 @ WkvT.
// ---------------------------------------------------------------------------
__global__ __launch_bounds__(256, 2)
void proj_all(const ushort_t* __restrict__ A1, const ushort_t* __restrict__ A2,
              const ushort_t* __restrict__ Wqt, const ushort_t* __restrict__ Wkvt,
              const float* __restrict__ bqv, const float* __restrict__ bkv,
              ushort_t* __restrict__ Qr, ushort_t* __restrict__ Kr,
              ushort_t* __restrict__ Vt)
{
    __shared__ ushort_t As[128 * 72];
    __shared__ ushort_t Bs[128 * 72];

    const int t = threadIdx.x;
    const int lane = t & 63;
    const int wv = t >> 6;
    const int wr = wv >> 1, wc = wv & 1;
    const int c = lane & 15, g = lane >> 4;
    const int m0 = blockIdx.y * 128;
    const int nblk = blockIdx.x;

    const ushort_t* A;
    const ushort_t* Wt;
    const float* bias;
    int n0;
    if (nblk < 8) { A = A1; Wt = Wqt;  bias = bqv; n0 = nblk * 128; }
    else          { A = A2; Wt = Wkvt; bias = bkv; n0 = (nblk - 8) * 128; }
    const bool isQ = (nblk < 8);

    f32x4 acc[4][4];
    const f32x4 zero4 = {0.f, 0.f, 0.f, 0.f};
#pragma unroll
    for (int mi = 0; mi < 4; ++mi)
#pragma unroll
        for (int ni = 0; ni < 4; ++ni) acc[mi][ni] = zero4;

    const int srow[4] = { (t + 0)   >> 3, (t + 256) >> 3, (t + 512) >> 3, (t + 768) >> 3 };
    const int skq     = (t & 7) * 8;

    short8 a_reg[4], b_reg[4];
#pragma unroll
    for (int rep = 0; rep < 4; ++rep) {
        a_reg[rep] = ld8(A  + (size_t)(m0 + srow[rep]) * 1024 + skq);
        b_reg[rep] = ld8(Wt + (size_t)(n0 + srow[rep]) * 1024 + skq);
    }

    for (int it = 0; it < 16; ++it) {
#pragma unroll
        for (int rep = 0; rep < 4; ++rep) {
            *reinterpret_cast<short8*>(&As[srow[rep] * 72 + skq]) = a_reg[rep];
            *reinterpret_cast<short8*>(&Bs[srow[rep] * 72 + skq]) = b_reg[rep];
        }
        __syncthreads();
        if (it < 15) {
            const int k1 = (it + 1) * 64;
#pragma unroll
            for (int rep = 0; rep < 4; ++rep) {
                a_reg[rep] = ld8(A  + (size_t)(m0 + srow[rep]) * 1024 + k1 + skq);
                b_reg[rep] = ld8(Wt + (size_t)(n0 + srow[rep]) * 1024 + k1 + skq);
            }
        }
#pragma unroll
        for (int kk = 0; kk < 64; kk += 32) {
            short8 afr[4], bfr[4];
#pragma unroll
            for (int mi = 0; mi < 4; ++mi)
                afr[mi] = ld8(&As[(wr * 64 + mi * 16 + c) * 72 + kk + 8 * g]);
#pragma unroll
            for (int ni = 0; ni < 4; ++ni)
                bfr[ni] = ld8(&Bs[(wc * 64 + ni * 16 + c) * 72 + kk + 8 * g]);
#pragma unroll
            for (int mi = 0; mi < 4; ++mi)
#pragma unroll
                for (int ni = 0; ni < 4; ++ni)
                    acc[mi][ni] = __builtin_amdgcn_mfma_f32_16x16x32_bf16(
                        afr[mi], bfr[ni], acc[mi][ni], 0, 0, 0);
        }
        __syncthreads();
    }

#pragma unroll
    for (int mi = 0; mi < 4; ++mi) {
#pragma unroll
        for (int ni = 0; ni < 4; ++ni) {
            const int n = n0 + wc * 64 + ni * 16 + c;
            const float bb = bias[n];
#pragma unroll
            for (int j = 0; j < 4; ++j) {
                const int m = m0 + wr * 64 + mi * 16 + 4 * g + j;
                const int b = m >> 11, s = m & 2047;
                const ushort_t val = f2bf(acc[mi][ni][j] + bb);
                if (isQ) {
                    Qr[((size_t)((b * 16 + (n >> 6)) * 2048 + s)) * 64 + (n & 63)] = val;
                } else if (n < 1024) {
                    Kr[((size_t)((b * 16 + (n >> 6)) * 2048 + s)) * 64 + (n & 63)] = val;
                } else {
                    const int np = n - 1024;
                    Vt[(size_t)((b * 16 + (np >> 6)) * 64 + (np & 63)) * 2048 + s] = val;
                }
            }
        }
    }
}

// ---------------------------------------------------------------------------
// Fallback projection (r3/r8-proven): used if ws_size is too small for prep.
// ---------------------------------------------------------------------------
__global__ __launch_bounds__(256)
void proj_gemm(const float* __restrict__ A, const float* __restrict__ W,
               const float* __restrict__ bias, int N,
               ushort_t* __restrict__ outRow, ushort_t* __restrict__ outT)
{
    __shared__ ushort_t As[128 * 72];
    __shared__ ushort_t Bt[128 * 72];

    const int t = threadIdx.x;
    const int lane = t & 63;
    const int wv = t >> 6;
    const int wr = wv >> 1, wc = wv & 1;
    const int c = lane & 15, g = lane >> 4;
    const int m0 = blockIdx.y * 128, n0 = blockIdx.x * 128;

    f32x4 acc[4][4];
    const f32x4 zero4 = {0.f, 0.f, 0.f, 0.f};
#pragma unroll
    for (int mi = 0; mi < 4; ++mi)
#pragma unroll
        for (int ni = 0; ni < 4; ++ni) acc[mi][ni] = zero4;

    for (int it = 0; it < 16; ++it) {
        const int k0 = it * 64;
        {
            const int kq = (t & 15) * 4;
            int r = t >> 4;
#pragma unroll
            for (int rep = 0; rep < 8; ++rep, r += 16) {
                float4 v = *reinterpret_cast<const float4*>(
                    A + (size_t)(m0 + r) * 1024 + k0 + kq);
                ushort_t* dst = &As[r * 72 + kq];
                dst[0] = f2bf(v.x); dst[1] = f2bf(v.y);
                dst[2] = f2bf(v.z); dst[3] = f2bf(v.w);
            }
        }
        {
            const int nq = (t & 31) * 4;
            const int kr = t >> 5;
#pragma unroll
            for (int rep = 0; rep < 8; ++rep) {
                const int k = kr + 8 * rep;
                float4 v = *reinterpret_cast<const float4*>(
                    W + (size_t)(k0 + k) * N + n0 + nq);
                Bt[(nq + 0) * 72 + k] = f2bf(v.x);
                Bt[(nq + 1) * 72 + k] = f2bf(v.y);
                Bt[(nq + 2) * 72 + k] = f2bf(v.z);
                Bt[(nq + 3) * 72 + k] = f2bf(v.w);
            }
        }
        __syncthreads();
#pragma unroll
        for (int kk = 0; kk < 64; kk += 32) {
            short8 afr[4], bfr[4];
#pragma unroll
            for (int mi = 0; mi < 4; ++mi)
                afr[mi] = ld8(&As[(wr * 64 + mi * 16 + c) * 72 + kk + 8 * g]);
#pragma unroll
            for (int ni = 0; ni < 4; ++ni)
                bfr[ni] = ld8(&Bt[(wc * 64 + ni * 16 + c) * 72 + kk + 8 * g]);
#pragma unroll
            for (int mi = 0; mi < 4; ++mi)
#pragma unroll
                for (int ni = 0; ni < 4; ++ni)
                    acc[mi][ni] = __builtin_amdgcn_mfma_f32_16x16x32_bf16(
                        afr[mi], bfr[ni], acc[mi][ni], 0, 0, 0);
        }
        __syncthreads();
    }

#pragma unroll
    for (int mi = 0; mi < 4; ++mi) {
#pragma unroll
        for (int ni = 0; ni < 4; ++ni) {
            const int n = n0 + wc * 64 + ni * 16 + c;
            const float bb = bias[n];
#pragma unroll
            for (int j = 0; j < 4; ++j) {
                const int m = m0 + wr * 64 + mi * 16 + 4 * g + j;
                const int b = m >> 11, s = m & 2047;
                const ushort_t val = f2bf(acc[mi][ni][j] + bb);
                if (outT != nullptr && n >= 1024) {
                    const int np = n - 1024;
                    const int hh = np >> 6, d = np & 63;
                    outT[(size_t)((b * 16 + hh) * 64 + d) * 2048 + s] = val;
                } else {
                    const int hh = n >> 6, d = n & 63;
                    outRow[((size_t)((b * 16 + hh) * 2048 + s)) * 64 + d] = val;
                }
            }
        }
    }
}

// ---------------------------------------------------------------------------
// Flash attention (r10 structure, q-halved): fixed-max softmax (v_exp_f32),
// PV^T, LDS double-buffered staging. Each wave owns 16 q-rows (one MFMA
// N-tile); block = 64 q-rows; grid = 32 bh x 32 qtiles = 1024 blocks
// -> 4 blocks/CU. Per-wave registers ~halved vs r10 so 4 waves/SIMD fit
// WITHOUT forcing the allocator (r12 lesson: forced caps => spill).
// ---------------------------------------------------------------------------
DEV void attn_body(const ushort_t* __restrict__ Kh, const ushort_t* __restrict__ Vh,
                   const float* __restrict__ crb, int kv_next,
                   const ushort_t* KsC, const ushort_t* VsC,
                   ushort_t* KsN, ushort_t* VsN,
                   int c, int g, int rk, int ck, int rv, int cv,
                   const short8 (&bq)[2],
                   float4 (&CC)[2][2], float4 (&CN)[2][2],
                   f32x4 (&accv)[4], float& lst, float& a0s, float& a1s)
{
    const f32x4 zero4 = {0.f, 0.f, 0.f, 0.f};
    const float SCL = 0.18033688011112042f;  // (1/8) * log2(e)

    const short8 kreg = ld8(Kh + (size_t)(kv_next + rk) * 64 + ck);
    const short8 vreg = ld8(Vh + (size_t)rv * 2048 + kv_next + cv);
    {
        const float* cp0 = crb + (size_t)(kv_next + 4 * g) * 2;
        CN[0][0] = *reinterpret_cast<const float4*>(cp0);
        CN[0][1] = *reinterpret_cast<const float4*>(cp0 + 4);
        const float* cp1 = crb + (size_t)(kv_next + 16 + 4 * g) * 2;
        CN[1][0] = *reinterpret_cast<const float4*>(cp1);
        CN[1][1] = *reinterpret_cast<const float4*>(cp1 + 4);
    }
    __builtin_amdgcn_sched_barrier(0);

    short8 KC[2][2];
#pragma unroll
    for (int ct = 0; ct < 2; ++ct)
#pragma unroll
        for (int st = 0; st < 2; ++st)
            KC[ct][st] = ld8(&KsC[(ct * 16 + c) * 72 + st * 32 + 8 * g]);
    short8 VC[4];
#pragma unroll
    for (int dt = 0; dt < 4; ++dt) {
        const short4_t vlo = *reinterpret_cast<const short4_t*>(&VsC[(dt * 16 + c) * 40 + 4 * g]);
        const short4_t vhi = *reinterpret_cast<const short4_t*>(&VsC[(dt * 16 + c) * 40 + 4 * g + 16]);
        VC[dt] = __builtin_shufflevector(vlo, vhi, 0, 1, 2, 3, 4, 5, 6, 7);
    }

    // QK^T (swapped): lane holds S^T[kv=16ct+4g+j][q=c]
    f32x4 sc[2];
#pragma unroll
    for (int ct = 0; ct < 2; ++ct) {
        f32x4 z = zero4;
        z = __builtin_amdgcn_mfma_f32_16x16x32_bf16(KC[ct][0], bq[0], z, 0, 0, 0);
        z = __builtin_amdgcn_mfma_f32_16x16x32_bf16(KC[ct][1], bq[1], z, 0, 0, 0);
        sc[ct] = z;
    }

    // fixed-max softmax + rank-2 cr accumulation
    float e[2][4];
    float lc = lst, a0c = a0s, a1c = a1s;
#pragma unroll
    for (int ct = 0; ct < 2; ++ct) {
        const float cr0[4] = {CC[ct][0].x, CC[ct][0].z, CC[ct][1].x, CC[ct][1].z};
        const float cr1[4] = {CC[ct][0].y, CC[ct][0].w, CC[ct][1].y, CC[ct][1].w};
#pragma unroll
        for (int j = 0; j < 4; ++j) {
            const float ev = fast_exp2(sc[ct][j] * SCL);
            e[ct][j] = ev;
            lc  += ev;
            a0c += ev * cr0[j];
            a1c += ev * cr1[j];
        }
    }
    lst = lc; a0s = a0c; a1s = a1c;
    int4 wv_;
    wv_.x = (int)pk_bf16(e[0][0], e[0][1]);
    wv_.y = (int)pk_bf16(e[0][2], e[0][3]);
    wv_.z = (int)pk_bf16(e[1][0], e[1][1]);
    wv_.w = (int)pk_bf16(e[1][2], e[1][3]);
    const short8 pa = __builtin_bit_cast(short8, wv_);

    // PV^T: A=V gathered in the same kv-slot permutation as P
#pragma unroll
    for (int dt = 0; dt < 4; ++dt)
        accv[dt] = __builtin_amdgcn_mfma_f32_16x16x32_bf16(VC[dt], pa, accv[dt], 0, 0, 0);

    *reinterpret_cast<short8*>(&KsN[rk * 72 + ck]) = kreg;
    *reinterpret_cast<short8*>(&VsN[rv * 40 + cv]) = vreg;
    __syncthreads();
}

__global__ __launch_bounds__(256, 2)
void attn_kernel(const ushort_t* __restrict__ Qr, const ushort_t* __restrict__ Kr,
                 const ushort_t* __restrict__ Vt, const float* __restrict__ cr,
                 const float* __restrict__ Wmo, const float* __restrict__ bmo,
                 float* __restrict__ out)
{
    __shared__ ushort_t Ks[2][32 * 72];
    __shared__ ushort_t Vs[2][64 * 40];

    const int t = threadIdx.x;
    const int w = t >> 6, lane = t & 63;
    const int c = lane & 15, g = lane >> 4;
    const int rk = t >> 3, ck = (t & 7) * 8;
    const int rv = t >> 2, cv = (t & 3) * 8;

    // XCD swizzle: gid%8 ~ XCD; each XCD sees 4 distinct (b,h) pairs.
    const int gid = blockIdx.x;
    const int bh = (gid & 7) + 8 * ((gid >> 3) & 3);
    const int xt = gid >> 5;                 // 0..31
    const int b = bh >> 4, hh = bh & 15;
    const int qb = xt * 64 + w * 16;         // one 16-row q tile per wave

    const ushort_t* Qh = Qr + (size_t)bh * (2048 * 64);
    const ushort_t* Kh = Kr + (size_t)bh * (2048 * 64);
    const ushort_t* Vh = Vt + (size_t)bh * (64 * 2048);
    const float*   crb = cr + (size_t)b * (2048 * 2);

    short8 bq[2];
#pragma unroll
    for (int st = 0; st < 2; ++st)
        bq[st] = ld8(Qh + (size_t)(qb + c) * 64 + st * 32 + 8 * g);

    f32x4 accv[4];
    const f32x4 zero4 = {0.f, 0.f, 0.f, 0.f};
#pragma unroll
    for (int dt = 0; dt < 4; ++dt) accv[dt] = zero4;

    float lst = 0.f, a0s = 0.f, a1s = 0.f;
    float4 cA[2][2], cB[2][2];

    {
        const short8 k0 = ld8(Kh + (size_t)rk * 64 + ck);
        const short8 v0 = ld8(Vh + (size_t)rv * 2048 + cv);
        *reinterpret_cast<short8*>(&Ks[0][rk * 72 + ck]) = k0;
        *reinterpret_cast<short8*>(&Vs[0][rv * 40 + cv]) = v0;
        const float* cp0 = crb + (size_t)(4 * g) * 2;
        cA[0][0] = *reinterpret_cast<const float4*>(cp0);
        cA[0][1] = *reinterpret_cast<const float4*>(cp0 + 4);
        const float* cp1 = crb + (size_t)(16 + 4 * g) * 2;
        cA[1][0] = *reinterpret_cast<const float4*>(cp1);
        cA[1][1] = *reinterpret_cast<const float4*>(cp1 + 4);
    }
    __syncthreads();

    for (int i = 0; i < 32; ++i) {
        const int kvb = i * 64;
        attn_body(Kh, Vh, crb, kvb + 32,
                  &Ks[0][0], &Vs[0][0], &Ks[1][0], &Vs[1][0],
                  c, g, rk, ck, rv, cv, bq, cA, cB, accv, lst, a0s, a1s);
        attn_body(Kh, Vh, crb, (kvb + 64) & 2047,
                  &Ks[1][0], &Vs[1][0], &Ks[0][0], &Vs[0][0],
                  c, g, rk, ck, rv, cv, bq, cB, cA, accv, lst, a0s, a1s);
    }

    // reduce stats across g (kv-subsets): every lane gets q=c totals
    lst += __shfl_xor(lst, 16, 64); lst += __shfl_xor(lst, 32, 64);
    a0s += __shfl_xor(a0s, 16, 64); a0s += __shfl_xor(a0s, 32, 64);
    a1s += __shfl_xor(a1s, 16, 64); a1s += __shfl_xor(a1s, 32, 64);

    // epilogue: accv[dt] reg j -> q = qb+c, d = dt*16+4g+j
    const int q = qb + c;
    const float inv = 1.f / lst;
    const float a0 = a0s * inv, a1 = a1s * inv;
#pragma unroll
    for (int dt = 0; dt < 4; ++dt) {
        const int d = hh * 64 + dt * 16 + 4 * g;
        const float4 w0 = *reinterpret_cast<const float4*>(Wmo + d);
        const float4 w1 = *reinterpret_cast<const float4*>(Wmo + 1024 + d);
        const float4 bm = *reinterpret_cast<const float4*>(bmo + d);
        const size_t oidx = ((size_t)(b * 2048 + q)) * 1024 + d;
        float4 hv, mv;
        hv.x = accv[dt][0] * inv; hv.y = accv[dt][1] * inv;
        hv.z = accv[dt][2] * inv; hv.w = accv[dt][3] * inv;
        mv.x = a0 * w0.x + a1 * w1.x + bm.x;
        mv.y = a0 * w0.y + a1 * w1.y + bm.y;
        mv.z = a0 * w0.z + a1 * w1.z + bm.z;
        mv.w = a0 * w0.w + a1 * w1.w + bm.w;
        *reinterpret_cast<float4*>(out + oidx) = hv;
        *reinterpret_cast<float4*>(out + 4194304 + oidx) = mv;
    }
}

// ---------------------------------------------------------------------------
extern "C" void kernel_launch(void* const* d_in, const int* in_sizes, int n_in,
                              void* d_out, int out_size, void* d_ws, size_t ws_size,
                              hipStream_t stream)
{
    const float* i1  = (const float*)d_in[0];
    const float* i2  = (const float*)d_in[1];
    const float* cr  = (const float*)d_in[2];
    const float* Wq  = (const float*)d_in[3];
    const float* bq  = (const float*)d_in[4];
    const float* Wkv = (const float*)d_in[5];
    const float* bkv = (const float*)d_in[6];
    const float* Wmo = (const float*)d_in[7];
    const float* bmo = (const float*)d_in[8];
    float* out = (float*)d_out;

    ushort_t* Qr = (ushort_t*)d_ws;          // [2,16,2048,64] bf16 (8 MB)
    ushort_t* Kr = Qr + 4194304;             // [2,16,2048,64] bf16 (8 MB)
    ushort_t* Vt = Kr + 4194304;             // [2,16,64,2048] bf16 (8 MB)

    // fast path needs 46 MB of ws: + A1(8) A2(8) Wqt(2) Wkvt(4)
    if (ws_size >= 48234496ULL) {
        ushort_t* A1   = Vt + 4194304;
        ushort_t* A2   = A1 + 4194304;
        ushort_t* Wqt  = A2 + 4194304;
        ushort_t* Wkvt = Wqt + 1048576;
        cvt_bf16<<<dim3(2048), dim3(256), 0, stream>>>(i1, A1);
        cvt_bf16<<<dim3(2048), dim3(256), 0, stream>>>(i2, A2);
        tcvt_bf16<<<dim3(16, 16), dim3(256), 0, stream>>>(Wq, Wqt, 1024, 1024);
        tcvt_bf16<<<dim3(32, 16), dim3(256), 0, stream>>>(Wkv, Wkvt, 1024, 2048);
        proj_all<<<dim3(24, 32), dim3(256), 0, stream>>>(A1, A2, Wqt, Wkvt, bq, bkv, Qr, Kr, Vt);
    } else {
        proj_gemm<<<dim3(8, 32), dim3(256), 0, stream>>>(i1, Wq, bq, 1024, Qr, nullptr);
        proj_gemm<<<dim3(16, 32), dim3(256), 0, stream>>>(i2, Wkv, bkv, 2048, Kr, Vt);
    }
    attn_kernel<<<dim3(1024), dim3(256), 0, stream>>>(Qr, Kr, Vt, cr, Wmo, bmo, out);
}